// Round 13
// baseline (633.226 us; speedup 1.0000x reference)
//
#include <hip/hip_runtime.h>
#include <hip/hip_bf16.h>

// ===== pv MEASUREMENT + qkv occupancy fix =====
// Base = R10 (222us best).
// qkv: output-split across blockIdx.y (y=0 q/k, y=1 v) -> 2x blocks, ~4
//   waves/SIMD, per-output FMA order unchanged (bit-identical), weight
//   traffic unchanged (same rows read once per 16-row tile).
// attn_pv: body x REP_PV=8 (rotated tile order, last-writer-wins) to surface
//   its counters in the top-5. True pv = visible/8.
//
// B=2, N=4096 (64x64), DIM=128, NH=4, dh=32
// d_out = out[2,4096,128] fp32 ++ attn[2,4,4096,4096] fp32
// rel_index IGNORED: idx = (rn-rm+63)*127 + (cn-cm+63), rn=n>>6, cn=n&63.
// ws: q16 2MB | kTile 2MB | vTile 2MB | bt16 129KB | inv 128KB = 6,552,064 B.

typedef short s16x8 __attribute__((ext_vector_type(8)));
typedef float f32x4 __attribute__((ext_vector_type(4)));

#define LOG2E 1.4426950408889634f
#define SCALE_L2 (0.17677669529663687f * LOG2E)   // 32^-0.5 * log2(e)
#define REP_PV 8

__device__ __forceinline__ float bf2f(short u) {
  union { unsigned int i; float f; } v;
  v.i = ((unsigned int)(unsigned short)u) << 16;
  return v.f;
}
__device__ __forceinline__ short f2bf(float f) {
  union { float f; unsigned int i; } v; v.f = f;
  unsigned int r = v.i + 0x7FFFu + ((v.i >> 16) & 1u);  // RNE
  return (short)(r >> 16);
}

// ---------------- Kernel 0: bias table -> bf16 [h][idx], pre-scaled --------
__global__ __launch_bounds__(256)
void bt_kernel(const float* __restrict__ bias_table, short* __restrict__ bt16) {
  int idx = blockIdx.x * 256 + threadIdx.x;
  int h = blockIdx.y;
  if (idx < 16129) bt16[h * 16129 + idx] = f2bf(bias_table[idx * 4 + h] * LOG2E);
}

// ---------------- Kernel 1: QKV projections, output-split -------------------
// blockIdx.y = 0: q/k (oc = tid); = 1: v (vd = tid&127, 8 rows/half).
__global__ __launch_bounds__(256)
void qkv_kernel(const float* __restrict__ x,
                const float* __restrict__ q_w, const float* __restrict__ q_b,
                const float* __restrict__ kv_w, const float* __restrict__ kv_b,
                short* __restrict__ q16, short* __restrict__ kTile, short* __restrict__ vTile)
{
  __shared__ float xs[16][128];
  const int tid = threadIdx.x;
  const int row0 = blockIdx.x * 16;
  {
    const float4* src = (const float4*)(x + (size_t)row0 * 128);
    float4* dst = (float4*)&xs[0][0];
    dst[tid]       = src[tid];
    dst[tid + 256] = src[tid + 256];
  }
  __syncthreads();

  const int b  = row0 >> 12;
  const int nn0 = row0 & 4095;
  const int ctb = nn0 >> 4;

  if (blockIdx.y == 0) {
    // ---- q/k: oc = tid in [0,256) ----
    const int oc = tid;
    const float* wrow = (oc < 128) ? (q_w + (size_t)oc*128) : (kv_w + (size_t)(oc-128)*128);
    const float bias = (oc < 128) ? q_b[oc] : kv_b[oc-128];
    float acc[16];
    #pragma unroll
    for (int r = 0; r < 16; ++r) acc[r] = bias;
    const float4* w4 = (const float4*)wrow;
    #pragma unroll 4
    for (int k4 = 0; k4 < 32; ++k4) {
      float4 wv = w4[k4];
      #pragma unroll
      for (int r = 0; r < 16; ++r) {
        float4 xv = *(const float4*)&xs[r][k4 << 2];
        acc[r] = fmaf(xv.x, wv.x, acc[r]); acc[r] = fmaf(xv.y, wv.y, acc[r]);
        acc[r] = fmaf(xv.z, wv.z, acc[r]); acc[r] = fmaf(xv.w, wv.w, acc[r]);
      }
    }
    if (oc < 128) {
      const int hh = oc >> 5, d = oc & 31;
      short* dstp = q16 + ((size_t)((b<<2) + hh)*4096 + nn0)*32 + d;
      #pragma unroll
      for (int r = 0; r < 16; ++r) dstp[(size_t)r * 32] = f2bf(acc[r]);
    } else {
      const int j = oc - 128, hh = j >> 5, d32 = j & 31;
      const int lg = d32 >> 3, e = d32 & 7;
      short* dstp = kTile + ((((size_t)((b<<2)+hh)*256 + ctb)*64) + (lg<<4))*8 + e;
      #pragma unroll
      for (int r = 0; r < 16; ++r) dstp[(size_t)r * 8] = f2bf(acc[r]);
    }
  } else {
    // ---- v: vd = tid&127, 8 rows per thread-half ----
    const int vd = tid & 127;
    const int rb = (tid >> 7) << 3;
    const float* wrow = kv_w + (size_t)(128 + vd)*128;
    float acc[8];
    const float bias = kv_b[128 + vd];
    #pragma unroll
    for (int r = 0; r < 8; ++r) acc[r] = bias;
    const float4* w4 = (const float4*)wrow;
    #pragma unroll 4
    for (int k4 = 0; k4 < 32; ++k4) {
      float4 wv = w4[k4];
      #pragma unroll
      for (int r = 0; r < 8; ++r) {
        float4 xv = *(const float4*)&xs[rb + r][k4 << 2];
        acc[r] = fmaf(xv.x, wv.x, acc[r]); acc[r] = fmaf(xv.y, wv.y, acc[r]);
        acc[r] = fmaf(xv.z, wv.z, acc[r]); acc[r] = fmaf(xv.w, wv.w, acc[r]);
      }
    }
    const int hh = vd >> 5, dv = vd & 31;
    const int half = dv >> 4, l15v = dv & 15;
    short* base = vTile + (((size_t)((b<<2)+hh)*256 + ctb)*64)*8;
    #pragma unroll
    for (int r = 0; r < 8; ++r) {
      int m15 = rb + r;
      int lg = m15 >> 2, e = (m15 & 3) + (half << 2);
      base[(size_t)((lg<<4) + l15v)*8 + e] = f2bf(acc[r]);
    }
  }
}

// ---------------- Kernel 2a: PV + row sums (R10 body, x REP_PV) -------------
__global__ __launch_bounds__(256, 8)
void attn_pv_kernel(const short* __restrict__ q16, const short* __restrict__ kTile,
                    const short* __restrict__ vTile, const short* __restrict__ bt16,
                    float* __restrict__ outp, float* __restrict__ inv_ws)
{
  __shared__ float accL[4][64][9];
  __shared__ float wsum[4][16];
  __shared__ float invL[16];

  const int tid  = threadIdx.x;
  const int wv   = tid >> 6;
  const int lane = tid & 63;
  const int l15  = lane & 15;
  const int lg   = lane >> 4;
  const int bh   = blockIdx.x & 7;
  const int row0 = (blockIdx.x >> 3) << 4;
  const int h    = bh & 3;
  const int b    = bh >> 2;

  const short* kt  = kTile + (size_t)bh * (256*512);
  const short* vt  = vTile + (size_t)bh * (256*512);
  const short* bth = bt16 + h * 16129;

  s16x8 qfrag = *(const s16x8*)(q16 + (size_t)bh*(4096*32) + (size_t)(row0 + l15)*32 + (lg<<3));
  const int rn = row0 >> 6;
  const int c0 = row0 & 63;
  const int lanoff = l15 - (lg << 2);
  const int ct0 = wv << 6;

  for (int rep = 0; rep < REP_PV; ++rep) {
    f32x4 acc0a = {0.f,0.f,0.f,0.f}, acc0b = {0.f,0.f,0.f,0.f};
    f32x4 acc1a = {0.f,0.f,0.f,0.f}, acc1b = {0.f,0.f,0.f,0.f};
    float sum = 0.f;

    #define PASS_A_BODY(CT, A0, A1)                                              \
    {                                                                            \
      s16x8 kfrag = *(const s16x8*)(kt + (size_t)(CT)*512 + (lane<<3));          \
      f32x4 z = {0.f,0.f,0.f,0.f};                                               \
      f32x4 d = __builtin_amdgcn_mfma_f32_16x16x32_bf16(kfrag, qfrag, z, 0,0,0); \
      int sidx = (rn - ((CT)>>2) + 63)*127 + (c0 - (((CT)&3)<<4) + 63);          \
      const short* bp = bth + (sidx + lanoff);                                   \
      float e0 = __builtin_amdgcn_exp2f(fmaf(d[0], SCALE_L2, bf2f(bp[ 0])));     \
      float e1 = __builtin_amdgcn_exp2f(fmaf(d[1], SCALE_L2, bf2f(bp[-1])));     \
      float e2 = __builtin_amdgcn_exp2f(fmaf(d[2], SCALE_L2, bf2f(bp[-2])));     \
      float e3 = __builtin_amdgcn_exp2f(fmaf(d[3], SCALE_L2, bf2f(bp[-3])));     \
      sum += (e0+e1) + (e2+e3);                                                  \
      s16x8 pfrag;                                                               \
      pfrag[0]=f2bf(e0); pfrag[1]=f2bf(e1); pfrag[2]=f2bf(e2); pfrag[3]=f2bf(e3);\
      pfrag[4]=0; pfrag[5]=0; pfrag[6]=0; pfrag[7]=0;                            \
      s16x8 vv = *(const s16x8*)(vt + (size_t)(CT)*512 + (lane<<3));             \
      s16x8 vfa = {vv[0],vv[1],vv[2],vv[3],0,0,0,0};                             \
      s16x8 vfb = {vv[4],vv[5],vv[6],vv[7],0,0,0,0};                             \
      A0 = __builtin_amdgcn_mfma_f32_16x16x32_bf16(pfrag, vfa, A0, 0, 0, 0);     \
      A1 = __builtin_amdgcn_mfma_f32_16x16x32_bf16(pfrag, vfb, A1, 0, 0, 0);     \
    }

    // rotated tile order per rep: same 64 tiles, not hoistable across reps
    #pragma unroll 2
    for (int i2 = 0; i2 < 32; ++i2) {
      PASS_A_BODY(ct0 + ((2*i2     + (rep<<3)) & 63), acc0a, acc1a)
      PASS_A_BODY(ct0 + ((2*i2 + 1 + (rep<<3)) & 63), acc0b, acc1b)
    }
    #undef PASS_A_BODY

    f32x4 acc0 = acc0a + acc0b;
    f32x4 acc1 = acc1a + acc1b;

    float s = sum;
    s += __shfl_xor(s, 16);
    s += __shfl_xor(s, 32);
    if (lg == 0) wsum[wv][l15] = s;
    #pragma unroll
    for (int j = 0; j < 4; ++j) {
      accL[wv][lane][j]     = acc0[j];
      accL[wv][lane][4 + j] = acc1[j];
    }
    __syncthreads();

    if (tid < 16) {
      float t = (wsum[0][tid] + wsum[1][tid]) + (wsum[2][tid] + wsum[3][tid]);
      float iv = 1.0f / t;
      invL[tid] = iv;
      inv_ws[(size_t)bh*4096 + row0 + tid] = iv;
    }
    __syncthreads();

    if (wv == 0) {
      float* os = outp + ((size_t)(b*4096 + row0))*128 + (h<<5);
      #pragma unroll
      for (int s8 = 0; s8 < 8; ++s8) {
        int j = s8 & 3, half = s8 >> 2;
        float v = (accL[0][lane][s8] + accL[1][lane][s8])
                + (accL[2][lane][s8] + accL[3][lane][s8]);
        int r = (lg << 2) + j;
        os[(size_t)r*128 + (half << 4) + l15] = v * invL[r];
      }
    }
    __syncthreads();   // protect accL/wsum reuse across reps
  }
}

// ---------------- Kernel 2b: attn write, LDS-staged full-line stores --------
__global__ __launch_bounds__(256, 8)
void attn_wr_kernel(const short* __restrict__ q16, const short* __restrict__ kTile,
                    const short* __restrict__ bt16, const float* __restrict__ inv_ws,
                    float* __restrict__ attn)
{
  __shared__ float stage[4][16][64];         // 16 KB, per-wave strips

  const int tid  = threadIdx.x;
  const int wv   = tid >> 6;
  const int lane = tid & 63;
  const int l15  = lane & 15;
  const int lg   = lane >> 4;
  const int bh   = blockIdx.x & 7;
  const int row0 = (blockIdx.x >> 3) << 4;
  const int h    = bh & 3;

  const short* kt  = kTile + (size_t)bh * (256*512);
  const short* bth = bt16 + h * 16129;

  s16x8 qfrag = *(const s16x8*)(q16 + (size_t)bh*(4096*32) + (size_t)(row0 + l15)*32 + (lg<<3));
  const int rn = row0 >> 6;
  const int c0 = row0 & 63;
  const int lanoff = l15 - (lg << 2);
  const float inv = inv_ws[(size_t)bh*4096 + row0 + l15];

  float (*st)[64] = stage[wv];
  const int ct0 = wv << 6;

  const int srow = lane >> 4;                // 0..3
  const int c4r  = lane & 15;                // chunk within row

  for (int g = 0; g < 16; ++g) {             // 16 groups of 4 tiles
    #pragma unroll
    for (int t = 0; t < 4; ++t) {
      const int ct = ct0 + (g << 2) + t;
      s16x8 kfrag = *(const s16x8*)(kt + (size_t)ct*512 + (lane<<3));
      f32x4 z = {0.f,0.f,0.f,0.f};
      f32x4 d = __builtin_amdgcn_mfma_f32_16x16x32_bf16(kfrag, qfrag, z, 0, 0, 0);
      int sidx = (rn - (ct>>2) + 63)*127 + (c0 - ((ct&3)<<4) + 63);
      const short* bp = bth + (sidx + lanoff);
      float o0 = __builtin_amdgcn_exp2f(fmaf(d[0], SCALE_L2, bf2f(bp[ 0]))) * inv;
      float o1 = __builtin_amdgcn_exp2f(fmaf(d[1], SCALE_L2, bf2f(bp[-1]))) * inv;
      float o2 = __builtin_amdgcn_exp2f(fmaf(d[2], SCALE_L2, bf2f(bp[-2]))) * inv;
      float o3 = __builtin_amdgcn_exp2f(fmaf(d[3], SCALE_L2, bf2f(bp[-3]))) * inv;
      const int c4 = (t << 2) + lg;
      float* p = &st[l15][(c4 ^ l15) << 2];
      p[0] = o0; p[1] = o1; p[2] = o2; p[3] = o3;
    }
    const size_t gcol = (size_t)(ct0 + (g << 2)) << 4;
    #pragma unroll
    for (int rg = 0; rg < 4; ++rg) {
      const int rr = (rg << 2) + srow;
      f32x4 o = *(const f32x4*)&st[rr][(c4r ^ rr) << 2];
      float* dst = attn + ((size_t)(bh*4096 + row0 + rr))*4096 + gcol + (c4r << 2);
      __builtin_nontemporal_store(o, (f32x4*)dst);
    }
  }
}

// ---------------- Kernel 3: output projection (R10-identical) ---------------
__global__ __launch_bounds__(256)
void proj_kernel(float* __restrict__ out, const float* __restrict__ proj_w,
                 const float* __restrict__ proj_b)
{
  __shared__ float xs[16][128];
  const int tid = threadIdx.x;
  const int row0 = blockIdx.x * 16;
  {
    const float4* src = (const float4*)(out + (size_t)row0 * 128);
    float4* dst = (float4*)&xs[0][0];
    dst[tid]       = src[tid];
    dst[tid + 256] = src[tid + 256];
  }
  __syncthreads();
  const int oc = tid & 127;
  const int rb = (tid >> 7) << 3;
  float acc[8];
  const float bias = proj_b[oc];
  #pragma unroll
  for (int r = 0; r < 8; ++r) acc[r] = bias;
  const float4* w4 = (const float4*)(proj_w + (size_t)oc*128);
  #pragma unroll 4
  for (int k4 = 0; k4 < 32; ++k4) {
    float4 wv = w4[k4];
    #pragma unroll
    for (int r = 0; r < 8; ++r) {
      float4 xv = *(const float4*)&xs[rb + r][k4 << 2];
      acc[r] = fmaf(xv.x, wv.x, acc[r]); acc[r] = fmaf(xv.y, wv.y, acc[r]);
      acc[r] = fmaf(xv.z, wv.z, acc[r]); acc[r] = fmaf(xv.w, wv.w, acc[r]);
    }
  }
  #pragma unroll
  for (int r = 0; r < 8; ++r)
    out[(size_t)(row0 + rb + r)*128 + oc] = acc[r];
}

extern "C" void kernel_launch(void* const* d_in, const int* in_sizes, int n_in,
                              void* d_out, int out_size, void* d_ws, size_t ws_size,
                              hipStream_t stream) {
  const float* x          = (const float*)d_in[0];
  const float* q_w        = (const float*)d_in[1];
  const float* q_b        = (const float*)d_in[2];
  const float* kv_w       = (const float*)d_in[3];
  const float* kv_b       = (const float*)d_in[4];
  const float* proj_w     = (const float*)d_in[5];
  const float* proj_b     = (const float*)d_in[6];
  const float* bias_table = (const float*)d_in[7];

  float* out  = (float*)d_out;                     // [2,4096,128]
  float* attn = (float*)d_out + 1048576;           // [2,4,4096,4096]

  char* ws = (char*)d_ws;                          // 6,552,064 B used
  short* q16    = (short*)(ws);                    // 2 MiB
  short* kTile  = (short*)(ws + (2u << 20));       // 2 MiB
  short* vTile  = (short*)(ws + (4u << 20));       // 2 MiB
  short* bt16   = (short*)(ws + 6291456);          // 129,032 B
  float* inv_ws = (float*)(ws + 6420992);          // 131,072 B

  bt_kernel<<<dim3(64, 4), dim3(256), 0, stream>>>(bias_table, bt16);
  qkv_kernel<<<dim3(512, 2), dim3(256), 0, stream>>>(x, q_w, q_b, kv_w, kv_b, q16, kTile, vTile);
  attn_pv_kernel<<<dim3(2048), dim3(256), 0, stream>>>(q16, kTile, vTile, bt16, out, inv_ws);
  attn_wr_kernel<<<dim3(2048), dim3(256), 0, stream>>>(q16, kTile, bt16, inv_ws, attn);
  proj_kernel<<<dim3(512), dim3(256), 0, stream>>>(out, proj_w, proj_b);
}

// Round 14
// 205.572 us; speedup vs baseline: 3.0803x; 3.0803x over previous
//
#include <hip/hip_runtime.h>
#include <hip/hip_bf16.h>

// B=2, N=4096 (64x64), DIM=128, NH=4, dh=32
// d_out = out[2,4096,128] fp32 ++ attn[2,4,4096,4096] fp32
// rel_index IGNORED: idx = (rn-rm+63)*127 + (cn-cm+63), rn=n>>6, cn=n&63.
// ws: q16 2MB | kTile 2MB | vTile 2MB | bt f32 258KB | inv 128KB = 6,680,592 B.
// kTile/vTile in MFMA fragment order (R6): per K-tile a wave loads ONE
// contiguous 1KB dwordx4.
// R12/R13 isolation: qkv ~27 (occupancy), pv ~70 (VALUBusy 70% -> VALU-bound),
// wr ~102 (write-floor ~85). R14: cut pv VALU/tile -- cvt_pk_bf16 packing,
// f32 bias loads (f32x4u), K=16 PV MFMAs (no zero-padding), ones-MFMA row sums
// (no sum adds / shfl). wr gets f32 bias. qkv keeps R13 y-split.

typedef short s16x8 __attribute__((ext_vector_type(8)));
typedef short s16x4 __attribute__((ext_vector_type(4)));
typedef float f32x4 __attribute__((ext_vector_type(4)));
typedef float f32x4u __attribute__((ext_vector_type(4), aligned(4)));
typedef unsigned u32x2 __attribute__((ext_vector_type(2)));

#define LOG2E 1.4426950408889634f
#define SCALE_L2 (0.17677669529663687f * LOG2E)   // 32^-0.5 * log2(e)

__device__ __forceinline__ short f2bf(float f) {
  union { float f; unsigned int i; } v; v.f = f;
  unsigned int r = v.i + 0x7FFFu + ((v.i >> 16) & 1u);  // RNE
  return (short)(r >> 16);
}
__device__ __forceinline__ unsigned cvt_pk_bf16(float lo, float hi) {
  unsigned r;
  asm("v_cvt_pk_bf16_f32 %0, %1, %2" : "=v"(r) : "v"(lo), "v"(hi));
  return r;  // [15:0]=bf16(lo), [31:16]=bf16(hi), RNE
}

// PV MFMA, K=16 (exact-fit fragments); fallback pads to K=32.
__device__ __forceinline__ f32x4 pv_mfma(s16x4 a, s16x4 b, f32x4 c) {
#if __has_builtin(__builtin_amdgcn_mfma_f32_16x16x16bf16_1k)
  return __builtin_amdgcn_mfma_f32_16x16x16bf16_1k(a, b, c, 0, 0, 0);
#else
  s16x8 a8 = {a[0], a[1], a[2], a[3], 0, 0, 0, 0};
  s16x8 b8 = {b[0], b[1], b[2], b[3], 0, 0, 0, 0};
  return __builtin_amdgcn_mfma_f32_16x16x32_bf16(a8, b8, c, 0, 0, 0);
#endif
}

// ---------------- Kernel 0: bias table -> f32 [h][idx], pre-scaled ---------
__global__ __launch_bounds__(256)
void bt_kernel(const float* __restrict__ bias_table, float* __restrict__ bt) {
  int idx = blockIdx.x * 256 + threadIdx.x;
  int h = blockIdx.y;
  if (idx < 16129) bt[h * 16129 + idx] = bias_table[idx * 4 + h] * LOG2E;
}

// ---------------- Kernel 1: QKV projections, output-split (R13) -------------
__global__ __launch_bounds__(256)
void qkv_kernel(const float* __restrict__ x,
                const float* __restrict__ q_w, const float* __restrict__ q_b,
                const float* __restrict__ kv_w, const float* __restrict__ kv_b,
                short* __restrict__ q16, short* __restrict__ kTile, short* __restrict__ vTile)
{
  __shared__ float xs[16][128];
  const int tid = threadIdx.x;
  const int row0 = blockIdx.x * 16;
  {
    const float4* src = (const float4*)(x + (size_t)row0 * 128);
    float4* dst = (float4*)&xs[0][0];
    dst[tid]       = src[tid];
    dst[tid + 256] = src[tid + 256];
  }
  __syncthreads();

  const int b  = row0 >> 12;
  const int nn0 = row0 & 4095;
  const int ctb = nn0 >> 4;

  if (blockIdx.y == 0) {
    const int oc = tid;
    const float* wrow = (oc < 128) ? (q_w + (size_t)oc*128) : (kv_w + (size_t)(oc-128)*128);
    const float bias = (oc < 128) ? q_b[oc] : kv_b[oc-128];
    float acc[16];
    #pragma unroll
    for (int r = 0; r < 16; ++r) acc[r] = bias;
    const float4* w4 = (const float4*)wrow;
    #pragma unroll 4
    for (int k4 = 0; k4 < 32; ++k4) {
      float4 wv = w4[k4];
      #pragma unroll
      for (int r = 0; r < 16; ++r) {
        float4 xv = *(const float4*)&xs[r][k4 << 2];
        acc[r] = fmaf(xv.x, wv.x, acc[r]); acc[r] = fmaf(xv.y, wv.y, acc[r]);
        acc[r] = fmaf(xv.z, wv.z, acc[r]); acc[r] = fmaf(xv.w, wv.w, acc[r]);
      }
    }
    if (oc < 128) {
      const int hh = oc >> 5, d = oc & 31;
      short* dstp = q16 + ((size_t)((b<<2) + hh)*4096 + nn0)*32 + d;
      #pragma unroll
      for (int r = 0; r < 16; ++r) dstp[(size_t)r * 32] = f2bf(acc[r]);
    } else {
      const int j = oc - 128, hh = j >> 5, d32 = j & 31;
      const int lg = d32 >> 3, e = d32 & 7;
      short* dstp = kTile + ((((size_t)((b<<2)+hh)*256 + ctb)*64) + (lg<<4))*8 + e;
      #pragma unroll
      for (int r = 0; r < 16; ++r) dstp[(size_t)r * 8] = f2bf(acc[r]);
    }
  } else {
    const int vd = tid & 127;
    const int rb = (tid >> 7) << 3;
    const float* wrow = kv_w + (size_t)(128 + vd)*128;
    float acc[8];
    const float bias = kv_b[128 + vd];
    #pragma unroll
    for (int r = 0; r < 8; ++r) acc[r] = bias;
    const float4* w4 = (const float4*)wrow;
    #pragma unroll 4
    for (int k4 = 0; k4 < 32; ++k4) {
      float4 wv = w4[k4];
      #pragma unroll
      for (int r = 0; r < 8; ++r) {
        float4 xv = *(const float4*)&xs[rb + r][k4 << 2];
        acc[r] = fmaf(xv.x, wv.x, acc[r]); acc[r] = fmaf(xv.y, wv.y, acc[r]);
        acc[r] = fmaf(xv.z, wv.z, acc[r]); acc[r] = fmaf(xv.w, wv.w, acc[r]);
      }
    }
    const int hh = vd >> 5, dv = vd & 31;
    const int half = dv >> 4, l15v = dv & 15;
    short* base = vTile + (((size_t)((b<<2)+hh)*256 + ctb)*64)*8;
    #pragma unroll
    for (int r = 0; r < 8; ++r) {
      int m15 = rb + r;
      int lg = m15 >> 2, e = (m15 & 3) + (half << 2);
      base[(size_t)((lg<<4) + l15v)*8 + e] = f2bf(acc[r]);
    }
  }
}

// ---------------- Kernel 2a: PV + row sums, VALU-trimmed --------------------
// Per tile: 1 QK MFMA(K=32), f32x4u bias load, 4 exp2, 2 cvt_pk, 3 K=16 MFMAs
// (PV d-lo, PV d-hi, ones-rowsum). No f2bf chains, no padding movs, no shfl.
__global__ __launch_bounds__(256, 8)
void attn_pv_kernel(const short* __restrict__ q16, const short* __restrict__ kTile,
                    const short* __restrict__ vTile, const float* __restrict__ bt,
                    float* __restrict__ outp, float* __restrict__ inv_ws)
{
  __shared__ float accL[4][64][9];
  __shared__ float wsum[4][16];
  __shared__ float invL[16];

  const int tid  = threadIdx.x;
  const int wv   = tid >> 6;
  const int lane = tid & 63;
  const int l15  = lane & 15;
  const int lg   = lane >> 4;
  const int bh   = blockIdx.x & 7;
  const int row0 = (blockIdx.x >> 3) << 4;
  const int h    = bh & 3;
  const int b    = bh >> 2;

  const short* kt  = kTile + (size_t)bh * (256*512);
  const short* vt  = vTile + (size_t)bh * (256*512);
  const float* bth = bt + h * 16129;

  s16x8 qfrag = *(const s16x8*)(q16 + (size_t)bh*(4096*32) + (size_t)(row0 + l15)*32 + (lg<<3));
  const int rn = row0 >> 6;
  const int c0 = row0 & 63;
  const int lanoff = l15 - (lg << 2);

  const s16x4 ones4 = {(short)0x3F80, (short)0x3F80, (short)0x3F80, (short)0x3F80};

  f32x4 acc0a = {0.f,0.f,0.f,0.f}, acc0b = {0.f,0.f,0.f,0.f};
  f32x4 acc1a = {0.f,0.f,0.f,0.f}, acc1b = {0.f,0.f,0.f,0.f};
  f32x4 acc_s = {0.f,0.f,0.f,0.f};

  #define PASS_A_BODY(CT, A0, A1)                                              \
  {                                                                            \
    s16x8 kfrag = *(const s16x8*)(kt + (size_t)(CT)*512 + (lane<<3));          \
    f32x4 z = {0.f,0.f,0.f,0.f};                                               \
    f32x4 d = __builtin_amdgcn_mfma_f32_16x16x32_bf16(kfrag, qfrag, z, 0,0,0); \
    int sidx = (rn - ((CT)>>2) + 63)*127 + (c0 - (((CT)&3)<<4) + 63);          \
    f32x4u w = *(const f32x4u*)(bth + sidx + lanoff - 3);                      \
    float e0 = __builtin_amdgcn_exp2f(fmaf(d[0], SCALE_L2, w[3]));             \
    float e1 = __builtin_amdgcn_exp2f(fmaf(d[1], SCALE_L2, w[2]));             \
    float e2 = __builtin_amdgcn_exp2f(fmaf(d[2], SCALE_L2, w[1]));             \
    float e3 = __builtin_amdgcn_exp2f(fmaf(d[3], SCALE_L2, w[0]));             \
    u32x2 pk = {cvt_pk_bf16(e0, e1), cvt_pk_bf16(e2, e3)};                     \
    s16x4 pfrag = __builtin_bit_cast(s16x4, pk);                               \
    s16x8 vv = *(const s16x8*)(vt + (size_t)(CT)*512 + (lane<<3));             \
    s16x4 vfa = __builtin_shufflevector(vv, vv, 0, 1, 2, 3);                   \
    s16x4 vfb = __builtin_shufflevector(vv, vv, 4, 5, 6, 7);                   \
    A0 = pv_mfma(pfrag, vfa, A0);                                              \
    A1 = pv_mfma(pfrag, vfb, A1);                                              \
    acc_s = pv_mfma(pfrag, ones4, acc_s);                                      \
  }

  const int ct0 = wv << 6;
  #pragma unroll 2
  for (int i2 = 0; i2 < 32; ++i2) {
    PASS_A_BODY(ct0 + 2*i2,     acc0a, acc1a)
    PASS_A_BODY(ct0 + 2*i2 + 1, acc0b, acc1b)
  }
  #undef PASS_A_BODY

  f32x4 acc0 = acc0a + acc0b;
  f32x4 acc1 = acc1a + acc1b;

  // acc_s[j] = rowsum of q-row (4*lg + j), identical across l15 lanes
  if (l15 == 0) {
    #pragma unroll
    for (int j = 0; j < 4; ++j) wsum[wv][(lg << 2) + j] = acc_s[j];
  }
  #pragma unroll
  for (int j = 0; j < 4; ++j) {
    accL[wv][lane][j]     = acc0[j];
    accL[wv][lane][4 + j] = acc1[j];
  }
  __syncthreads();

  if (tid < 16) {
    float t = (wsum[0][tid] + wsum[1][tid]) + (wsum[2][tid] + wsum[3][tid]);
    float iv = 1.0f / t;
    invL[tid] = iv;
    inv_ws[(size_t)bh*4096 + row0 + tid] = iv;
  }
  __syncthreads();

  if (wv == 0) {
    float* os = outp + ((size_t)(b*4096 + row0))*128 + (h<<5);
    #pragma unroll
    for (int s = 0; s < 8; ++s) {
      int j = s & 3, half = s >> 2;
      float v = (accL[0][lane][s] + accL[1][lane][s])
              + (accL[2][lane][s] + accL[3][lane][s]);
      int r = (lg << 2) + j;
      os[(size_t)r*128 + (half << 4) + l15] = v * invL[r];
    }
  }
}

// ---------------- Kernel 2b: attn write, LDS-staged full-line stores --------
__global__ __launch_bounds__(256, 8)
void attn_wr_kernel(const short* __restrict__ q16, const short* __restrict__ kTile,
                    const float* __restrict__ bt, const float* __restrict__ inv_ws,
                    float* __restrict__ attn)
{
  __shared__ float stage[4][16][64];         // 16 KB, per-wave strips

  const int tid  = threadIdx.x;
  const int wv   = tid >> 6;
  const int lane = tid & 63;
  const int l15  = lane & 15;
  const int lg   = lane >> 4;
  const int bh   = blockIdx.x & 7;
  const int row0 = (blockIdx.x >> 3) << 4;
  const int h    = bh & 3;

  const short* kt  = kTile + (size_t)bh * (256*512);
  const float* bth = bt + h * 16129;

  s16x8 qfrag = *(const s16x8*)(q16 + (size_t)bh*(4096*32) + (size_t)(row0 + l15)*32 + (lg<<3));
  const int rn = row0 >> 6;
  const int c0 = row0 & 63;
  const int lanoff = l15 - (lg << 2);
  const float inv = inv_ws[(size_t)bh*4096 + row0 + l15];

  float (*st)[64] = stage[wv];
  const int ct0 = wv << 6;

  const int srow = lane >> 4;                // 0..3
  const int c4r  = lane & 15;                // chunk within row

  for (int g = 0; g < 16; ++g) {             // 16 groups of 4 tiles
    #pragma unroll
    for (int t = 0; t < 4; ++t) {
      const int ct = ct0 + (g << 2) + t;
      s16x8 kfrag = *(const s16x8*)(kt + (size_t)ct*512 + (lane<<3));
      f32x4 z = {0.f,0.f,0.f,0.f};
      f32x4 d = __builtin_amdgcn_mfma_f32_16x16x32_bf16(kfrag, qfrag, z, 0, 0, 0);
      int sidx = (rn - (ct>>2) + 63)*127 + (c0 - ((ct&3)<<4) + 63);
      f32x4u w = *(const f32x4u*)(bth + sidx + lanoff - 3);
      float o0 = __builtin_amdgcn_exp2f(fmaf(d[0], SCALE_L2, w[3])) * inv;
      float o1 = __builtin_amdgcn_exp2f(fmaf(d[1], SCALE_L2, w[2])) * inv;
      float o2 = __builtin_amdgcn_exp2f(fmaf(d[2], SCALE_L2, w[1])) * inv;
      float o3 = __builtin_amdgcn_exp2f(fmaf(d[3], SCALE_L2, w[0])) * inv;
      const int c4 = (t << 2) + lg;
      float* p = &st[l15][(c4 ^ l15) << 2];
      p[0] = o0; p[1] = o1; p[2] = o2; p[3] = o3;
    }
    const size_t gcol = (size_t)(ct0 + (g << 2)) << 4;
    #pragma unroll
    for (int rg = 0; rg < 4; ++rg) {
      const int rr = (rg << 2) + srow;
      f32x4 o = *(const f32x4*)&st[rr][(c4r ^ rr) << 2];
      float* dst = attn + ((size_t)(bh*4096 + row0 + rr))*4096 + gcol + (c4r << 2);
      __builtin_nontemporal_store(o, (f32x4*)dst);
    }
  }
}

// ---------------- Kernel 3: output projection (R10-identical) ---------------
__global__ __launch_bounds__(256)
void proj_kernel(float* __restrict__ out, const float* __restrict__ proj_w,
                 const float* __restrict__ proj_b)
{
  __shared__ float xs[16][128];
  const int tid = threadIdx.x;
  const int row0 = blockIdx.x * 16;
  {
    const float4* src = (const float4*)(out + (size_t)row0 * 128);
    float4* dst = (float4*)&xs[0][0];
    dst[tid]       = src[tid];
    dst[tid + 256] = src[tid + 256];
  }
  __syncthreads();
  const int oc = tid & 127;
  const int rb = (tid >> 7) << 3;
  float acc[8];
  const float bias = proj_b[oc];
  #pragma unroll
  for (int r = 0; r < 8; ++r) acc[r] = bias;
  const float4* w4 = (const float4*)(proj_w + (size_t)oc*128);
  #pragma unroll 4
  for (int k4 = 0; k4 < 32; ++k4) {
    float4 wv = w4[k4];
    #pragma unroll
    for (int r = 0; r < 8; ++r) {
      float4 xv = *(const float4*)&xs[rb + r][k4 << 2];
      acc[r] = fmaf(xv.x, wv.x, acc[r]); acc[r] = fmaf(xv.y, wv.y, acc[r]);
      acc[r] = fmaf(xv.z, wv.z, acc[r]); acc[r] = fmaf(xv.w, wv.w, acc[r]);
    }
  }
  #pragma unroll
  for (int r = 0; r < 8; ++r)
    out[(size_t)(row0 + rb + r)*128 + oc] = acc[r];
}

extern "C" void kernel_launch(void* const* d_in, const int* in_sizes, int n_in,
                              void* d_out, int out_size, void* d_ws, size_t ws_size,
                              hipStream_t stream) {
  const float* x          = (const float*)d_in[0];
  const float* q_w        = (const float*)d_in[1];
  const float* q_b        = (const float*)d_in[2];
  const float* kv_w       = (const float*)d_in[3];
  const float* kv_b       = (const float*)d_in[4];
  const float* proj_w     = (const float*)d_in[5];
  const float* proj_b     = (const float*)d_in[6];
  const float* bias_table = (const float*)d_in[7];

  float* out  = (float*)d_out;                     // [2,4096,128]
  float* attn = (float*)d_out + 1048576;           // [2,4,4096,4096]

  char* ws = (char*)d_ws;                          // 6,680,592 B used (<10MB)
  short* q16    = (short*)(ws);                    // 2 MiB
  short* kTile  = (short*)(ws + (2u << 20));       // 2 MiB
  short* vTile  = (short*)(ws + (4u << 20));       // 2 MiB
  float* bt     = (float*)(ws + 6291456);          // 258,064 B [4][16129] f32 (xLOG2E)
  float* inv_ws = (float*)(ws + 6549520);          // 131,072 B [8][4096] f32

  bt_kernel<<<dim3(64, 4), dim3(256), 0, stream>>>(bias_table, bt);
  qkv_kernel<<<dim3(512, 2), dim3(256), 0, stream>>>(x, q_w, q_b, kv_w, kv_b, q16, kTile, vTile);
  attn_pv_kernel<<<dim3(2048), dim3(256), 0, stream>>>(q16, kTile, vTile, bt, out, inv_ws);
  attn_wr_kernel<<<dim3(2048), dim3(256), 0, stream>>>(q16, kTile, bt, inv_ws, attn);
  proj_kernel<<<dim3(512), dim3(256), 0, stream>>>(out, proj_w, proj_b);
}